// Round 3
// baseline (1663.531 us; speedup 1.0000x reference)
//
#include <hip/hip_runtime.h>
#include <hip/hip_bf16.h>

// MHA forward: B=4, S=2048, D=1024, H=16, dk=64.
// Inputs fp32, OUTPUT fp32 (reference dtype). bf16 MFMA operands, fp32 accum.
// ws layout (bf16 elems): Q[B,H,S,dk] | K[B,H,S,dk] | Vt[B,H,dk,S] | Hcat[B,S,D]

typedef short bf16x8 __attribute__((ext_vector_type(8)));   // 8 bf16 (4 VGPRs)
typedef float f32x4 __attribute__((ext_vector_type(4)));

#define D_MODEL 1024
#define SEQ     2048
#define BATCH   4
#define NHEAD   16
#define DK      64
#define LOG2E   1.44269504088896340736f

__device__ __forceinline__ bf16x8 load8(const __hip_bfloat16* p) {
    return *reinterpret_cast<const bf16x8*>(p);
}

__device__ __forceinline__ short f2b(float x) {
    __hip_bfloat16 h = __float2bfloat16(x);
    return *reinterpret_cast<short*>(&h);
}

// Load 8 consecutive fp32 and convert to a bf16x8 fragment (RNE).
__device__ __forceinline__ bf16x8 cvt8(const float* p) {
    f32x4 a = *reinterpret_cast<const f32x4*>(p);
    f32x4 b = *reinterpret_cast<const f32x4*>(p + 4);
    bf16x8 r;
    r[0] = f2b(a[0]); r[1] = f2b(a[1]); r[2] = f2b(a[2]); r[3] = f2b(a[3]);
    r[4] = f2b(b[0]); r[5] = f2b(b[1]); r[6] = f2b(b[2]); r[7] = f2b(b[3]);
    return r;
}

// ---------------------------------------------------------------------------
// QKV projection: out[m,n] = sum_k X[m,k] * W[n,k]   (Linear weight is [out,in])
// Block = 4 waves, tile 64x64. Wave: 16 rows x 64 cols (4 accs).
// z=0 -> Q [B,H,S,dk], z=1 -> K [B,H,S,dk], z=2 -> V^T [B,H,dk,S]
// ---------------------------------------------------------------------------
__global__ __launch_bounds__(256) void qkv_gemm(
    const float* __restrict__ X,
    const float* __restrict__ Wq,
    const float* __restrict__ Wk,
    const float* __restrict__ Wv,
    __hip_bfloat16* __restrict__ Qo,
    __hip_bfloat16* __restrict__ Ko,
    __hip_bfloat16* __restrict__ Vto)
{
    const int w    = threadIdx.x >> 6;
    const int lane = threadIdx.x & 63;
    const int l15  = lane & 15;
    const int quad = lane >> 4;
    const int blockN = blockIdx.x * 64;
    const int blockM = blockIdx.y * 64;
    const int z      = blockIdx.z;

    const float* W      = (z == 0) ? Wq : (z == 1) ? Wk : Wv;
    __hip_bfloat16* out = (z == 0) ? Qo : (z == 1) ? Ko : Vto;

    const int m0 = blockM + w * 16;
    f32x4 acc[4] = {{0.f,0.f,0.f,0.f},{0.f,0.f,0.f,0.f},
                    {0.f,0.f,0.f,0.f},{0.f,0.f,0.f,0.f}};

    // A frag: lane holds X[m0+l15][k + quad*8 + j], j=0..7
    const float* aPtr  = X + (size_t)(m0 + l15) * D_MODEL + quad * 8;
    // B frag: lane holds B[k=quad*8+j][n] = W[n][k+quad*8+j]
    const float* wBase = W + (size_t)(blockN + l15) * D_MODEL + quad * 8;

    for (int k = 0; k < D_MODEL; k += 32) {
        bf16x8 a = cvt8(aPtr + k);
        #pragma unroll
        for (int nt = 0; nt < 4; ++nt) {
            bf16x8 b = cvt8(wBase + (size_t)nt * 16 * D_MODEL + k);
            acc[nt] = __builtin_amdgcn_mfma_f32_16x16x32_bf16(a, b, acc[nt], 0, 0, 0);
        }
    }

    // C layout: row = quad*4 + r, col = l15
    #pragma unroll
    for (int nt = 0; nt < 4; ++nt) {
        int n = blockN + nt * 16 + l15;
        int h = n >> 6, d = n & 63;
        #pragma unroll
        for (int r = 0; r < 4; ++r) {
            int m = m0 + quad * 4 + r;
            int b = m >> 11, s = m & 2047;
            float v = acc[nt][r];
            if (z < 2) {
                out[((size_t)((b << 4) + h) * SEQ + s) * DK + d] = __float2bfloat16(v);
            } else {
                out[((size_t)((b << 4) + h) * DK + d) * SEQ + s] = __float2bfloat16(v);
            }
        }
    }
}

// ---------------------------------------------------------------------------
// Flash attention. Block = 4 waves = 64 q-rows of one (b,h); wave owns 16 rows.
// kv tile = 32. Scores via QK^T MFMA (fp32), online softmax with shfl-reduce
// over the 16-lane quad group, P -> LDS -> A-frag, P*V via MFMA against V^T.
// ---------------------------------------------------------------------------
__global__ __launch_bounds__(256) void flash_attn(
    const __hip_bfloat16* __restrict__ Q,
    const __hip_bfloat16* __restrict__ K,
    const __hip_bfloat16* __restrict__ Vt,
    __hip_bfloat16* __restrict__ H)
{
    __shared__ __align__(16) __hip_bfloat16 Plds[4][16][32];

    const int w    = threadIdx.x >> 6;
    const int lane = threadIdx.x & 63;
    const int l15  = lane & 15;
    const int quad = lane >> 4;
    const int bh   = blockIdx.y;
    const int b    = bh >> 4, h = bh & 15;
    const int q0   = blockIdx.x * 64 + w * 16;

    const __hip_bfloat16* Qb = Q  + (size_t)bh * SEQ * DK;
    const __hip_bfloat16* Kb = K  + (size_t)bh * SEQ * DK;
    const __hip_bfloat16* Vb = Vt + (size_t)bh * DK * SEQ;

    // Q fragments, reused across whole kv loop. A[m=l15][k=quad*8+j]
    bf16x8 qf[2];
    #pragma unroll
    for (int dh = 0; dh < 2; ++dh)
        qf[dh] = load8(Qb + (size_t)(q0 + l15) * DK + dh * 32 + quad * 8);

    f32x4 o[4] = {{0.f,0.f,0.f,0.f},{0.f,0.f,0.f,0.f},
                  {0.f,0.f,0.f,0.f},{0.f,0.f,0.f,0.f}};
    float mrow[4] = {-1e30f, -1e30f, -1e30f, -1e30f};
    float lrow[4] = {0.f, 0.f, 0.f, 0.f};

    for (int kv = 0; kv < SEQ; kv += 32) {
        // scores: two 16x16 tiles (kv halves), each = 2 MFMAs over d halves
        f32x4 s[2];
        #pragma unroll
        for (int kvh = 0; kvh < 2; ++kvh) {
            f32x4 c = {0.f, 0.f, 0.f, 0.f};
            #pragma unroll
            for (int dh = 0; dh < 2; ++dh) {
                bf16x8 kf = load8(Kb + (size_t)(kv + kvh * 16 + l15) * DK + dh * 32 + quad * 8);
                c = __builtin_amdgcn_mfma_f32_16x16x32_bf16(qf[dh], kf, c, 0, 0, 0);
            }
            s[kvh] = c * 0.125f;   // 1/sqrt(64)
        }

        // online softmax. C-layout row r lives in the 16 lanes of this quad.
        float alpha[4];
        #pragma unroll
        for (int r = 0; r < 4; ++r) {
            float t = fmaxf(s[0][r], s[1][r]);
            #pragma unroll
            for (int off = 1; off < 16; off <<= 1)
                t = fmaxf(t, __shfl_xor(t, off));
            float mnew = fmaxf(mrow[r], t);
            alpha[r] = exp2f((mrow[r] - mnew) * LOG2E);
            mrow[r] = mnew;
        }
        float p[2][4];
        #pragma unroll
        for (int r = 0; r < 4; ++r) {
            p[0][r] = exp2f((s[0][r] - mrow[r]) * LOG2E);
            p[1][r] = exp2f((s[1][r] - mrow[r]) * LOG2E);
            float t = p[0][r] + p[1][r];
            #pragma unroll
            for (int off = 1; off < 16; off <<= 1)
                t += __shfl_xor(t, off);
            lrow[r] = lrow[r] * alpha[r] + t;
        }
        #pragma unroll
        for (int t = 0; t < 4; ++t)
            #pragma unroll
            for (int r = 0; r < 4; ++r)
                o[t][r] *= alpha[r];

        // P (C layout) -> LDS -> A-frag layout
        #pragma unroll
        for (int r = 0; r < 4; ++r) {
            Plds[w][quad * 4 + r][l15]      = __float2bfloat16(p[0][r]);
            Plds[w][quad * 4 + r][16 + l15] = __float2bfloat16(p[1][r]);
        }
        __syncthreads();
        bf16x8 pf = load8(&Plds[w][l15][quad * 8]);

        // O += P * V : B[k=kv][n=d] = Vt[d][kv0+k], contiguous in k
        #pragma unroll
        for (int t = 0; t < 4; ++t) {
            bf16x8 vf = load8(Vb + (size_t)(t * 16 + l15) * SEQ + kv + quad * 8);
            o[t] = __builtin_amdgcn_mfma_f32_16x16x32_bf16(pf, vf, o[t], 0, 0, 0);
        }
        __syncthreads();
    }

    float inv_l[4];
    #pragma unroll
    for (int r = 0; r < 4; ++r) inv_l[r] = 1.0f / lrow[r];
    #pragma unroll
    for (int t = 0; t < 4; ++t) {
        int d = h * 64 + t * 16 + l15;
        #pragma unroll
        for (int r = 0; r < 4; ++r) {
            int sidx = q0 + quad * 4 + r;
            H[((size_t)b * SEQ + sidx) * D_MODEL + d] = __float2bfloat16(o[t][r] * inv_l[r]);
        }
    }
}

// ---------------------------------------------------------------------------
// Output projection: out[m,n] = sum_k Hcat[m,k] * Wh[n,k] + bias[n]
// Hcat is bf16 (ws); Wh/bias fp32 inputs; out is fp32 (reference output dtype).
// ---------------------------------------------------------------------------
__global__ __launch_bounds__(256) void out_gemm(
    const __hip_bfloat16* __restrict__ Hc,
    const float* __restrict__ Wh,
    const float* __restrict__ bias,
    float* __restrict__ out)
{
    const int w    = threadIdx.x >> 6;
    const int lane = threadIdx.x & 63;
    const int l15  = lane & 15;
    const int quad = lane >> 4;
    const int blockN = blockIdx.x * 64;
    const int blockM = blockIdx.y * 64;

    const int m0 = blockM + w * 16;
    f32x4 acc[4] = {{0.f,0.f,0.f,0.f},{0.f,0.f,0.f,0.f},
                    {0.f,0.f,0.f,0.f},{0.f,0.f,0.f,0.f}};

    const __hip_bfloat16* aPtr = Hc + (size_t)(m0 + l15) * D_MODEL + quad * 8;
    const float*         wBase = Wh + (size_t)(blockN + l15) * D_MODEL + quad * 8;

    for (int k = 0; k < D_MODEL; k += 32) {
        bf16x8 a = load8(aPtr + k);
        #pragma unroll
        for (int nt = 0; nt < 4; ++nt) {
            bf16x8 b = cvt8(wBase + (size_t)nt * 16 * D_MODEL + k);
            acc[nt] = __builtin_amdgcn_mfma_f32_16x16x32_bf16(a, b, acc[nt], 0, 0, 0);
        }
    }

    #pragma unroll
    for (int nt = 0; nt < 4; ++nt) {
        int n = blockN + nt * 16 + l15;
        float bv = bias[n];
        #pragma unroll
        for (int r = 0; r < 4; ++r) {
            int m = m0 + quad * 4 + r;
            out[(size_t)m * D_MODEL + n] = acc[nt][r] + bv;
        }
    }
}

// ---------------------------------------------------------------------------
extern "C" void kernel_launch(void* const* d_in, const int* in_sizes, int n_in,
                              void* d_out, int out_size, void* d_ws, size_t ws_size,
                              hipStream_t stream) {
    const float* X  = (const float*)d_in[0];
    const float* Wq = (const float*)d_in[1];
    const float* Wk = (const float*)d_in[2];
    const float* Wv = (const float*)d_in[3];
    const float* Wh = (const float*)d_in[4];
    const float* bh = (const float*)d_in[5];
    float* out = (float*)d_out;

    const size_t qkv_elems = (size_t)BATCH * NHEAD * SEQ * DK;  // 8,388,608
    __hip_bfloat16* Qw  = (__hip_bfloat16*)d_ws;
    __hip_bfloat16* Kw  = Qw  + qkv_elems;
    __hip_bfloat16* Vtw = Kw  + qkv_elems;
    __hip_bfloat16* Hw  = Vtw + qkv_elems;

    // M=8192 (B*S), N=1024; block tile 64x64
    qkv_gemm<<<dim3(D_MODEL / 64, (BATCH * SEQ) / 64, 3), 256, 0, stream>>>(
        X, Wq, Wk, Wv, Qw, Kw, Vtw);
    flash_attn<<<dim3(SEQ / 64, BATCH * NHEAD), 256, 0, stream>>>(Qw, Kw, Vtw, Hw);
    out_gemm<<<dim3(D_MODEL / 64, (BATCH * SEQ) / 64), 256, 0, stream>>>(Hw, Wh, bh, out);
}

// Round 4
// 675.595 us; speedup vs baseline: 2.4623x; 2.4623x over previous
//
#include <hip/hip_runtime.h>
#include <hip/hip_bf16.h>

// MHA forward: B=4, S=2048, D=1024, H=16, dk=64.
// Inputs fp32, output fp32. bf16 MFMA operands, fp32 accum.
// ws (bf16 elems): [Xb16|Hcat alias 8.4M] [Wqkv 3M] [Whb 1M] [Q 8.4M] [K 8.4M] [Vt 8.4M]

typedef short bf16x8 __attribute__((ext_vector_type(8)));   // 8 bf16 (4 VGPRs)
typedef float f32x4 __attribute__((ext_vector_type(4)));

#define D_MODEL 1024
#define SEQ     2048
#define BATCH   4
#define NHEAD   16
#define DK      64
#define LOG2E   1.44269504088896340736f

__device__ __forceinline__ bf16x8 load8(const __hip_bfloat16* p) {
    return *reinterpret_cast<const bf16x8*>(p);
}
__device__ __forceinline__ short f2b(float x) {
    __hip_bfloat16 h = __float2bfloat16(x);
    return *reinterpret_cast<short*>(&h);
}
__device__ __forceinline__ bf16x8 cvt8(const float* p) {
    f32x4 a = *reinterpret_cast<const f32x4*>(p);
    f32x4 b = *reinterpret_cast<const f32x4*>(p + 4);
    bf16x8 r;
    r[0] = f2b(a[0]); r[1] = f2b(a[1]); r[2] = f2b(a[2]); r[3] = f2b(a[3]);
    r[4] = f2b(b[0]); r[5] = f2b(b[1]); r[6] = f2b(b[2]); r[7] = f2b(b[3]);
    return r;
}
// async global->LDS, 16B per lane. lds ptr must be wave-uniform (HW adds lane*16).
__device__ __forceinline__ void gld_lds16(const __hip_bfloat16* g, __hip_bfloat16* l) {
    __builtin_amdgcn_global_load_lds(
        (const __attribute__((address_space(1))) unsigned int*)g,
        (__attribute__((address_space(3))) unsigned int*)l, 16, 0, 0);
}

// ---------------------------------------------------------------------------
// fp32 -> bf16 conversion, 8 elems/thread
// ---------------------------------------------------------------------------
__global__ __launch_bounds__(256) void cvt_f32_bf16(
    const float* __restrict__ src, __hip_bfloat16* __restrict__ dst, int n8)
{
    int i = blockIdx.x * 256 + threadIdx.x;
    if (i >= n8) return;
    *reinterpret_cast<bf16x8*>(dst + (size_t)i * 8) = cvt8(src + (size_t)i * 8);
}

// ---------------------------------------------------------------------------
// Fused QKV GEMM: C[m,n] = sum_k Xb[m,k]*Wqkv[n,k], M=8192, N=3072, K=1024.
// m97 structure: 128x128 tile, BK=32, global_load_lds(16B), 4 waves 2x2,
// wave = 4x4 tiles of 16x16x32 MFMA. Epilogue routes n>>10 -> Q / K / V^T.
// ---------------------------------------------------------------------------
__global__ __launch_bounds__(256) void qkv_gemm128(
    const __hip_bfloat16* __restrict__ Xb,
    const __hip_bfloat16* __restrict__ Wqkv,
    __hip_bfloat16* __restrict__ Qo,
    __hip_bfloat16* __restrict__ Ko,
    __hip_bfloat16* __restrict__ Vto)
{
    __shared__ __align__(16) __hip_bfloat16 At[128 * 32];   // [row][k] 8 KB
    __shared__ __align__(16) __hip_bfloat16 Bt[128 * 32];   // [n][k]  8 KB

    const int tid  = threadIdx.x;
    const int wave = tid >> 6, lane = tid & 63;
    const int l15  = lane & 15, quad = lane >> 4;
    const int wm   = wave >> 1, wn = wave & 1;
    const int bm0  = blockIdx.y * 128;
    const int bn0  = blockIdx.x * 128;

    // staging map: issue s covers row s*64 + wave*16 + lane/4, kcol (lane&3)*8
    const int srow = wave * 16 + (lane >> 2);
    const int scol = (lane & 3) * 8;
    const __hip_bfloat16* gA = Xb   + (size_t)(bm0 + srow) * 1024 + scol;
    const __hip_bfloat16* gB = Wqkv + (size_t)(bn0 + srow) * 1024 + scol;
    __hip_bfloat16* lA = At + wave * 512;   // wave-uniform base (bytes: wave*1024)
    __hip_bfloat16* lB = Bt + wave * 512;

    f32x4 acc[4][4];
    #pragma unroll
    for (int i = 0; i < 4; ++i)
        #pragma unroll
        for (int j = 0; j < 4; ++j) acc[i][j] = (f32x4){0.f, 0.f, 0.f, 0.f};

    for (int k0 = 0; k0 < 1024; k0 += 32) {
        gld_lds16(gA + k0,                      lA);
        gld_lds16(gA + (size_t)64 * 1024 + k0,  lA + 2048);
        gld_lds16(gB + k0,                      lB);
        gld_lds16(gB + (size_t)64 * 1024 + k0,  lB + 2048);
        __syncthreads();

        bf16x8 af[4], bfr[4];
        #pragma unroll
        for (int i = 0; i < 4; ++i)
            af[i] = load8(At + (wm * 64 + i * 16 + l15) * 32 + quad * 8);
        #pragma unroll
        for (int j = 0; j < 4; ++j)
            bfr[j] = load8(Bt + (wn * 64 + j * 16 + l15) * 32 + quad * 8);
        #pragma unroll
        for (int i = 0; i < 4; ++i)
            #pragma unroll
            for (int j = 0; j < 4; ++j)
                acc[i][j] = __builtin_amdgcn_mfma_f32_16x16x32_bf16(af[i], bfr[j], acc[i][j], 0, 0, 0);
        __syncthreads();
    }

    // epilogue: C row=quad*4+r col=l15 per 16x16 tile
    const int z = bn0 >> 10;   // block-uniform (1024 % 128 == 0)
    #pragma unroll
    for (int j = 0; j < 4; ++j) {
        int n  = bn0 + wn * 64 + j * 16 + l15;
        int nn = n & 1023;
        int h  = nn >> 6, d = nn & 63;
        #pragma unroll
        for (int i = 0; i < 4; ++i) {
            #pragma unroll
            for (int r = 0; r < 4; ++r) {
                int m = bm0 + wm * 64 + i * 16 + quad * 4 + r;
                int b = m >> 11, s = m & 2047;
                __hip_bfloat16 v = __float2bfloat16(acc[i][j][r]);
                if (z == 0)      Qo [((size_t)((b << 4) + h) * SEQ + s) * DK + d] = v;
                else if (z == 1) Ko [((size_t)((b << 4) + h) * SEQ + s) * DK + d] = v;
                else             Vto[((size_t)((b << 4) + h) * DK + d) * SEQ + s] = v;
            }
        }
    }
}

// ---------------------------------------------------------------------------
// Flash attention. Block = 4 waves = 64 q-rows of one (b,h); wave owns 16 rows.
// kv tile = 64, NO cross-wave barriers (each wave uses only Plds[w]).
// ---------------------------------------------------------------------------
__global__ __launch_bounds__(256) void flash_attn(
    const __hip_bfloat16* __restrict__ Q,
    const __hip_bfloat16* __restrict__ K,
    const __hip_bfloat16* __restrict__ Vt,
    __hip_bfloat16* __restrict__ H)
{
    __shared__ __align__(16) __hip_bfloat16 Plds[4][16][64];   // 8 KB

    const int w    = threadIdx.x >> 6;
    const int lane = threadIdx.x & 63;
    const int l15  = lane & 15;
    const int quad = lane >> 4;
    const int bh   = blockIdx.y;
    const int b    = bh >> 4, h = bh & 15;
    const int q0   = blockIdx.x * 64 + w * 16;

    const __hip_bfloat16* Qb = Q  + (size_t)bh * SEQ * DK;
    const __hip_bfloat16* Kb = K  + (size_t)bh * SEQ * DK;
    const __hip_bfloat16* Vb = Vt + (size_t)bh * DK * SEQ;

    bf16x8 qf[2];
    #pragma unroll
    for (int dh = 0; dh < 2; ++dh)
        qf[dh] = load8(Qb + (size_t)(q0 + l15) * DK + dh * 32 + quad * 8);

    f32x4 o[4] = {{0.f,0.f,0.f,0.f},{0.f,0.f,0.f,0.f},
                  {0.f,0.f,0.f,0.f},{0.f,0.f,0.f,0.f}};
    float mrow[4] = {-1e30f, -1e30f, -1e30f, -1e30f};
    float lrow[4] = {0.f, 0.f, 0.f, 0.f};

    for (int kv = 0; kv < SEQ; kv += 64) {
        // scores: four 16x16 kv-tiles, 2 MFMAs each over d halves
        f32x4 s[4];
        #pragma unroll
        for (int kvh = 0; kvh < 4; ++kvh) {
            f32x4 c = {0.f, 0.f, 0.f, 0.f};
            #pragma unroll
            for (int dh = 0; dh < 2; ++dh) {
                bf16x8 kf = load8(Kb + (size_t)(kv + kvh * 16 + l15) * DK + dh * 32 + quad * 8);
                c = __builtin_amdgcn_mfma_f32_16x16x32_bf16(qf[dh], kf, c, 0, 0, 0);
            }
            s[kvh] = c * 0.125f;   // 1/sqrt(64)
        }

        float alpha[4];
        #pragma unroll
        for (int r = 0; r < 4; ++r) {
            float t = fmaxf(fmaxf(s[0][r], s[1][r]), fmaxf(s[2][r], s[3][r]));
            #pragma unroll
            for (int off = 1; off < 16; off <<= 1)
                t = fmaxf(t, __shfl_xor(t, off));
            float mnew = fmaxf(mrow[r], t);
            alpha[r] = exp2f((mrow[r] - mnew) * LOG2E);
            mrow[r] = mnew;
        }
        float p[4][4];
        #pragma unroll
        for (int r = 0; r < 4; ++r) {
            float t = 0.f;
            #pragma unroll
            for (int kvh = 0; kvh < 4; ++kvh) {
                p[kvh][r] = exp2f((s[kvh][r] - mrow[r]) * LOG2E);
                t += p[kvh][r];
            }
            #pragma unroll
            for (int off = 1; off < 16; off <<= 1)
                t += __shfl_xor(t, off);
            lrow[r] = lrow[r] * alpha[r] + t;
        }
        #pragma unroll
        for (int t = 0; t < 4; ++t)
            #pragma unroll
            for (int r = 0; r < 4; ++r)
                o[t][r] *= alpha[r];

        // P (C layout) -> LDS -> A-frag layout (wave-local, no cross-wave sync)
        #pragma unroll
        for (int kvh = 0; kvh < 4; ++kvh)
            #pragma unroll
            for (int r = 0; r < 4; ++r)
                Plds[w][quad * 4 + r][kvh * 16 + l15] = __float2bfloat16(p[kvh][r]);
        asm volatile("s_waitcnt lgkmcnt(0)" ::: "memory");
        bf16x8 pf0 = load8(&Plds[w][l15][quad * 8]);
        bf16x8 pf1 = load8(&Plds[w][l15][32 + quad * 8]);

        #pragma unroll
        for (int t = 0; t < 4; ++t) {
            bf16x8 v0 = load8(Vb + (size_t)(t * 16 + l15) * SEQ + kv + quad * 8);
            o[t] = __builtin_amdgcn_mfma_f32_16x16x32_bf16(pf0, v0, o[t], 0, 0, 0);
            bf16x8 v1 = load8(Vb + (size_t)(t * 16 + l15) * SEQ + kv + 32 + quad * 8);
            o[t] = __builtin_amdgcn_mfma_f32_16x16x32_bf16(pf1, v1, o[t], 0, 0, 0);
        }
        asm volatile("s_waitcnt lgkmcnt(0)" ::: "memory");  // pf reads done before next P write
    }

    float inv_l[4];
    #pragma unroll
    for (int r = 0; r < 4; ++r) inv_l[r] = 1.0f / lrow[r];
    #pragma unroll
    for (int t = 0; t < 4; ++t) {
        int d = h * 64 + t * 16 + l15;
        #pragma unroll
        for (int r = 0; r < 4; ++r) {
            int sidx = q0 + quad * 4 + r;
            H[((size_t)b * SEQ + sidx) * D_MODEL + d] = __float2bfloat16(o[t][r] * inv_l[r]);
        }
    }
}

// ---------------------------------------------------------------------------
// Output projection, same 128-tile structure. A=Hcat bf16, B=Whb bf16,
// out fp32 + bias.
// ---------------------------------------------------------------------------
__global__ __launch_bounds__(256) void out_gemm128(
    const __hip_bfloat16* __restrict__ Hc,
    const __hip_bfloat16* __restrict__ Whb,
    const float* __restrict__ bias,
    float* __restrict__ out)
{
    __shared__ __align__(16) __hip_bfloat16 At[128 * 32];
    __shared__ __align__(16) __hip_bfloat16 Bt[128 * 32];

    const int tid  = threadIdx.x;
    const int wave = tid >> 6, lane = tid & 63;
    const int l15  = lane & 15, quad = lane >> 4;
    const int wm   = wave >> 1, wn = wave & 1;
    const int bm0  = blockIdx.y * 128;
    const int bn0  = blockIdx.x * 128;

    const int srow = wave * 16 + (lane >> 2);
    const int scol = (lane & 3) * 8;
    const __hip_bfloat16* gA = Hc  + (size_t)(bm0 + srow) * 1024 + scol;
    const __hip_bfloat16* gB = Whb + (size_t)(bn0 + srow) * 1024 + scol;
    __hip_bfloat16* lA = At + wave * 512;
    __hip_bfloat16* lB = Bt + wave * 512;

    f32x4 acc[4][4];
    #pragma unroll
    for (int i = 0; i < 4; ++i)
        #pragma unroll
        for (int j = 0; j < 4; ++j) acc[i][j] = (f32x4){0.f, 0.f, 0.f, 0.f};

    for (int k0 = 0; k0 < 1024; k0 += 32) {
        gld_lds16(gA + k0,                      lA);
        gld_lds16(gA + (size_t)64 * 1024 + k0,  lA + 2048);
        gld_lds16(gB + k0,                      lB);
        gld_lds16(gB + (size_t)64 * 1024 + k0,  lB + 2048);
        __syncthreads();

        bf16x8 af[4], bfr[4];
        #pragma unroll
        for (int i = 0; i < 4; ++i)
            af[i] = load8(At + (wm * 64 + i * 16 + l15) * 32 + quad * 8);
        #pragma unroll
        for (int j = 0; j < 4; ++j)
            bfr[j] = load8(Bt + (wn * 64 + j * 16 + l15) * 32 + quad * 8);
        #pragma unroll
        for (int i = 0; i < 4; ++i)
            #pragma unroll
            for (int j = 0; j < 4; ++j)
                acc[i][j] = __builtin_amdgcn_mfma_f32_16x16x32_bf16(af[i], bfr[j], acc[i][j], 0, 0, 0);
        __syncthreads();
    }

    #pragma unroll
    for (int j = 0; j < 4; ++j) {
        int n = bn0 + wn * 64 + j * 16 + l15;
        float bv = bias[n];
        #pragma unroll
        for (int i = 0; i < 4; ++i) {
            #pragma unroll
            for (int r = 0; r < 4; ++r) {
                int m = bm0 + wm * 64 + i * 16 + quad * 4 + r;
                out[(size_t)m * D_MODEL + n] = acc[i][j][r] + bv;
            }
        }
    }
}

// ---------------------------------------------------------------------------
extern "C" void kernel_launch(void* const* d_in, const int* in_sizes, int n_in,
                              void* d_out, int out_size, void* d_ws, size_t ws_size,
                              hipStream_t stream) {
    const float* X  = (const float*)d_in[0];
    const float* Wq = (const float*)d_in[1];
    const float* Wk = (const float*)d_in[2];
    const float* Wv = (const float*)d_in[3];
    const float* Wh = (const float*)d_in[4];
    const float* bh = (const float*)d_in[5];
    float* out = (float*)d_out;

    const size_t NX = (size_t)BATCH * SEQ * D_MODEL;      // 8,388,608
    const size_t NW = (size_t)D_MODEL * D_MODEL;          // 1,048,576

    __hip_bfloat16* Xb   = (__hip_bfloat16*)d_ws;         // aliases Hcat
    __hip_bfloat16* Hw   = Xb;
    __hip_bfloat16* Wqkv = Xb + NX;
    __hip_bfloat16* Whb  = Wqkv + 3 * NW;
    __hip_bfloat16* Qw   = Whb + NW;
    __hip_bfloat16* Kw   = Qw + NX;
    __hip_bfloat16* Vtw  = Kw + NX;

    cvt_f32_bf16<<<(int)(NX / 8 / 256), 256, 0, stream>>>(X,  Xb,            (int)(NX / 8));
    cvt_f32_bf16<<<(int)(NW / 8 / 256), 256, 0, stream>>>(Wq, Wqkv,          (int)(NW / 8));
    cvt_f32_bf16<<<(int)(NW / 8 / 256), 256, 0, stream>>>(Wk, Wqkv + NW,     (int)(NW / 8));
    cvt_f32_bf16<<<(int)(NW / 8 / 256), 256, 0, stream>>>(Wv, Wqkv + 2 * NW, (int)(NW / 8));
    cvt_f32_bf16<<<(int)(NW / 8 / 256), 256, 0, stream>>>(Wh, Whb,           (int)(NW / 8));

    // M=8192, N=3072 fused
    qkv_gemm128<<<dim3(3 * D_MODEL / 128, (BATCH * SEQ) / 128), 256, 0, stream>>>(
        Xb, Wqkv, Qw, Kw, Vtw);
    flash_attn<<<dim3(SEQ / 64, BATCH * NHEAD), 256, 0, stream>>>(Qw, Kw, Vtw, Hw);
    out_gemm128<<<dim3(D_MODEL / 128, (BATCH * SEQ) / 128), 256, 0, stream>>>(
        Hw, Whb, bh, out);
}